// Round 21
// baseline (287.170 us; speedup 1.0000x reference)
//
#include <hip/hip_runtime.h>
#include <hip/hip_bf16.h>
#include <cstdint>

#define NN 50000
#define NEDGE 800000
#define IND 256
#define NH 8
#define DHH 32
#define NET 8
#define LALPHA 0.2f
#define OD 256
#define CD 512
#define SCAN_BLOCKS 196   // 196*256 = 50176 >= NN+1
#define NBG 391           // gemm blocks: (NN+127)/128
#define NBH 391           // hist blocks: 391*512*4 = 800768 >= NEDGE

typedef __attribute__((ext_vector_type(8))) short short8;
typedef __attribute__((ext_vector_type(4))) float f32x4;
typedef __attribute__((ext_vector_type(4))) float f4v;
typedef __attribute__((ext_vector_type(2))) unsigned u2v;
typedef __attribute__((ext_vector_type(4))) int i4v;

__device__ __forceinline__ unsigned short f2bf(float x) {
  union { float f; unsigned u; } v; v.f = x;
  unsigned r = v.u + 0x7FFFu + ((v.u >> 16) & 1u);
  return (unsigned short)(r >> 16);
}
__device__ __forceinline__ float u2f_lo(unsigned w) {
  union { unsigned u; float f; } v; v.u = w << 16; return v.f;
}
__device__ __forceinline__ float u2f_hi(unsigned w) {
  union { unsigned u; float f; } v; v.u = w & 0xffff0000u; return v.f;
}

// ---- prep: W^T concat cast + zero cnt/done/flag (memsets folded in) ----
__global__ __launch_bounds__(256) void k_prep(const float* __restrict__ Wfc,
                                              const float* __restrict__ Wres,
                                              unsigned short* __restrict__ Wtb,
                                              int* __restrict__ cnt,
                                              int* __restrict__ done) {
  int id = blockIdx.x * 256 + threadIdx.x;
  int k = id >> 9;
  int c = id & 511;
  float v = (c < OD) ? Wfc[k * OD + c] : Wres[k * OD + (c - OD)];
  Wtb[(size_t)c * IND + k] = f2bf(v);
  if (id < NN / 4) {
    i4v z = {0, 0, 0, 0};
    *reinterpret_cast<i4v*>(cnt + id * 4) = z;
  }
  if (id == 0) { done[0] = 0; done[1] = 0; }
}

// ---- block-specialized: blocks <NBG (512 thr = 8 waves, 128 rows) do MFMA
// GEMM+scores (operand-swapped, coalesced writes); blocks >=NBG do histogram.
__global__ __launch_bounds__(512, 8) void k_gemm(const float* __restrict__ Af,
                                                 const unsigned short* __restrict__ Bt,
                                                 const float* __restrict__ bfc,
                                                 const float* __restrict__ bres,
                                                 const float* __restrict__ attn,
                                                 const int* __restrict__ dst,
                                                 int* __restrict__ cnt,
                                                 int* __restrict__ rk,
                                                 unsigned short* __restrict__ Hb,
                                                 unsigned short* __restrict__ Rb,
                                                 float* __restrict__ ssrc,
                                                 float* __restrict__ sdst) {
  __shared__ unsigned short Bs[64][272];   // 34.8 KB; 4 blocks/CU, 32 waves/CU
  int tid = threadIdx.x;

  if (blockIdx.x >= NBG) {
    // histogram block: 4 edges/thread, pure atomic work, no barriers
    int e0 = ((blockIdx.x - NBG) * 512 + tid) << 2;
    if (e0 < NEDGE) {
      i4v d4 = __builtin_nontemporal_load(reinterpret_cast<const i4v*>(dst + e0));
      i4v rv;
      rv.x = atomicAdd(&cnt[d4.x], 1);
      rv.y = atomicAdd(&cnt[d4.y], 1);
      rv.z = atomicAdd(&cnt[d4.z], 1);
      rv.w = atomicAdd(&cnt[d4.w], 1);
      __builtin_nontemporal_store(rv, reinterpret_cast<i4v*>(rk + e0));
    }
    return;
  }

  int wave = tid >> 6, lane = tid & 63;
  int row0 = blockIdx.x * 128;

  int sr = tid >> 3;            // staging: row 0..63
  int sc2 = (tid & 7) * 32;     // 32-elem k segment

  int cl = lane & 15;           // this thread's row-within-wave (C^T layout)
  int q = lane >> 4;            // col-quarter 0..3
  int arow = row0 + wave * 16 + cl;
  int lrow = arow < NN ? arow : NN - 1;    // clamp loads; stores guarded
  int akof = q * 8;
  short8 areg[8];
#pragma unroll
  for (int ks = 0; ks < 8; ++ks) {
    const float* p = Af + (size_t)lrow * IND + ks * 32 + akof;
    float4 f0 = *reinterpret_cast<const float4*>(p);
    float4 f1 = *reinterpret_cast<const float4*>(p + 4);
    unsigned short t8[8] = {f2bf(f0.x), f2bf(f0.y), f2bf(f0.z), f2bf(f0.w),
                            f2bf(f1.x), f2bf(f1.y), f2bf(f1.z), f2bf(f1.w)};
    areg[ks] = *reinterpret_cast<short8*>(t8);
  }

  for (int bn = 0; bn < 8; ++bn) {
    if (bn) __syncthreads();
#pragma unroll
    for (int j = 0; j < 4; ++j) {
      int k = sc2 + j * 8;
      short8 bv = *reinterpret_cast<const short8*>(Bt + (size_t)(bn * 64 + sr) * IND + k);
      *reinterpret_cast<short8*>(&Bs[sr][k]) = bv;
    }
    __syncthreads();

    f32x4 acc[4];
#pragma unroll
    for (int i = 0; i < 4; ++i) acc[i] = (f32x4){0.f, 0.f, 0.f, 0.f};
#pragma unroll
    for (int ks = 0; ks < 8; ++ks) {
#pragma unroll
      for (int nf = 0; nf < 4; ++nf) {
        // permuted col selection: thread ends up owning 16 contiguous cols
        int colsel = (cl & 12) * 4 + (nf << 2) + (cl & 3);
        short8 b = *reinterpret_cast<const short8*>(&Bs[colsel][ks * 32 + akof]);
        // swapped operands: acc[nf][r] = C[arow][bn*64 + q*16 + nf*4 + r]
        acc[nf] = __builtin_amdgcn_mfma_f32_16x16x32_bf16(b, areg[ks], acc[nf], 0, 0, 0);
      }
    }

    bool isH = (bn < 4);
    int g0 = bn * 64 + q * 16;
    float s0 = 0.f, d0 = 0.f;
    unsigned short o16[16];
    if (isH) {
      int h = bn * 2 + (q >> 1);
      int dd0 = (q & 1) * 16;
#pragma unroll
      for (int nf = 0; nf < 4; ++nf) {
        f4v b4 = *reinterpret_cast<const f4v*>(bfc + g0 + nf * 4);
        f4v as4 = *reinterpret_cast<const f4v*>(attn + h * 96 + dd0 + nf * 4);
        f4v ad4 = *reinterpret_cast<const f4v*>(attn + h * 96 + 32 + dd0 + nf * 4);
#pragma unroll
        for (int r = 0; r < 4; ++r) {
          float val = acc[nf][r] + b4[r];
          o16[nf * 4 + r] = f2bf(val);
          s0 = fmaf(val, as4[r], s0);
          d0 = fmaf(val, ad4[r], d0);
        }
      }
    } else {
#pragma unroll
      for (int nf = 0; nf < 4; ++nf) {
        f4v b4 = *reinterpret_cast<const f4v*>(bres + g0 - 256 + nf * 4);
#pragma unroll
        for (int r = 0; r < 4; ++r) {
          float val = acc[nf][r] + b4[r];
          o16[nf * 4 + r] = f2bf(val);
        }
      }
    }
    if (arow < NN) {
      unsigned short* dp = isH ? (Hb + (size_t)arow * 256 + g0)
                               : (Rb + (size_t)arow * 256 + (g0 - 256));
      *reinterpret_cast<short8*>(dp) = *reinterpret_cast<short8*>(o16);
      *reinterpret_cast<short8*>(dp + 8) = *reinterpret_cast<short8*>(o16 + 8);
    }
    if (isH) {
      s0 += __shfl_xor(s0, 16);   // combine the two col-halves of this head
      d0 += __shfl_xor(d0, 16);
      if (!(q & 1) && arow < NN) {
        int h = bn * 2 + (q >> 1);
        ssrc[arow * NH + h] = s0;
        sdst[arow * NH + h] = d0;
      }
    }
  }
}

// ---- fused scan + scatter: blocks <SCAN_BLOCKS scan cnt; last block scans
// block sums + se, then release-publishes. Blocks >=SCAN_BLOCKS spin (all 978
// blocks co-resident: 1KB LDS -> 8 blocks/CU capacity 2048) then scatter.
__global__ __launch_bounds__(256) void k_scansc(const int* __restrict__ cnt,
                                                int* __restrict__ off,
                                                int* __restrict__ bsum,
                                                int* __restrict__ done,
                                                const float* __restrict__ ee,
                                                const float* __restrict__ attn,
                                                float* __restrict__ se,
                                                int* __restrict__ boff,
                                                const int* __restrict__ src,
                                                const int* __restrict__ dst,
                                                const int* __restrict__ ety,
                                                const int* __restrict__ rk,
                                                int* __restrict__ csrp) {
  int tid = threadIdx.x;
  __shared__ int sh[256];
  __shared__ int lastFlag;

  if (blockIdx.x >= SCAN_BLOCKS) {
    // scatter block: wait for boff publication
    if (tid == 0) {
      while (__hip_atomic_load(done + 1, __ATOMIC_ACQUIRE, __HIP_MEMORY_SCOPE_AGENT) == 0)
        __builtin_amdgcn_s_sleep(8);
    }
    __syncthreads();
    int t = (blockIdx.x - SCAN_BLOCKS) * 256 + tid;
    int e0 = t << 2;
    if (e0 >= NEDGE) return;
    i4v s4 = __builtin_nontemporal_load(reinterpret_cast<const i4v*>(src + e0));
    i4v d4 = __builtin_nontemporal_load(reinterpret_cast<const i4v*>(dst + e0));
    i4v t4 = __builtin_nontemporal_load(reinterpret_cast<const i4v*>(ety + e0));
    i4v r4 = __builtin_nontemporal_load(reinterpret_cast<const i4v*>(rk + e0));
#pragma unroll
    for (int j = 0; j < 4; ++j) {
      int s = (j == 0) ? s4.x : (j == 1) ? s4.y : (j == 2) ? s4.z : s4.w;
      int d = (j == 0) ? d4.x : (j == 1) ? d4.y : (j == 2) ? d4.z : d4.w;
      int et = (j == 0) ? t4.x : (j == 1) ? t4.y : (j == 2) ? t4.z : t4.w;
      int r = (j == 0) ? r4.x : (j == 1) ? r4.y : (j == 2) ? r4.z : r4.w;
      csrp[off[d] + boff[d >> 8] + r] = (s << 8) | et;
    }
    return;
  }

  int gi = blockIdx.x * 256 + tid;
  int c = (gi < NN) ? cnt[gi] : 0;
  sh[tid] = c;
  __syncthreads();
#pragma unroll
  for (int d = 1; d < 256; d <<= 1) {
    int v = (tid >= d) ? sh[tid - d] : 0;
    __syncthreads();
    sh[tid] += v;
    __syncthreads();
  }
  off[gi] = sh[tid] - c;
  if (tid == 255) {
    bsum[blockIdx.x] = sh[255];
    __threadfence();
    lastFlag = (atomicAdd(done, 1) == SCAN_BLOCKS - 1);
  }
  __syncthreads();
  if (!lastFlag) return;
  __threadfence();
  int cb = (tid < SCAN_BLOCKS)
               ? __hip_atomic_load(&bsum[tid], __ATOMIC_ACQUIRE, __HIP_MEMORY_SCOPE_AGENT)
               : 0;
  __syncthreads();
  sh[tid] = cb;
  __syncthreads();
#pragma unroll
  for (int d = 1; d < 256; d <<= 1) {
    int v = (tid >= d) ? sh[tid - d] : 0;
    __syncthreads();
    sh[tid] += v;
    __syncthreads();
  }
  boff[tid] = sh[tid] - cb;
  __syncthreads();
  if (tid == 0) {
    __threadfence();
    __hip_atomic_store(done + 1, 1, __ATOMIC_RELEASE, __HIP_MEMORY_SCOPE_AGENT);
  }
  // se[et,h]: tid = h*32 + dd
  int h = tid >> 5, dd = tid & 31;
  float ae = attn[h * 96 + 64 + dd];
  for (int et = 0; et < NET; ++et) {
    float p = ee[et * OD + tid] * ae;
#pragma unroll
    for (int off2 = 16; off2; off2 >>= 1) p += __shfl_xor(p, off2, 32);
    if (dd == 0) se[et * NH + h] = p;
  }
}

// ---- fused edge-scoring + aggregation: 1 wave/node; per 8-edge chunk,
// subphase A computes p(edge=g, head=lane&7), then __shfl redistributes.
__global__ __launch_bounds__(256) void k_fuse(const unsigned short* __restrict__ Hb,
                                              const unsigned short* __restrict__ Rb,
                                              const int* __restrict__ csrp,
                                              const float* __restrict__ ssrc,
                                              const float* __restrict__ sdst,
                                              const float* __restrict__ se,
                                              const int* __restrict__ off,
                                              const int* __restrict__ boff,
                                              float* __restrict__ out) {
  __shared__ float sse[64];
  int tid = threadIdx.x;
  if (tid < 64) sse[tid] = se[tid];
  __syncthreads();
  int v = blockIdx.x * 4 + (tid >> 6);
  int lane = tid & 63;
  int g = lane >> 3;       // subphase A: edge slot; agg phase: head (same value)
  int hA = lane & 7;       // subphase A: head
  int lo = off[v] + boff[v >> 8];
  int hi = off[v + 1] + boff[(v + 1) >> 8];
  int n = hi - lo;
  float sd = sdst[v * NH + hA];
  unsigned lane4 = (unsigned)(lane << 2);
  float a0 = 0.f, a1 = 0.f, a2 = 0.f, a3 = 0.f, dsum = 0.f;
  for (int i = 0; i < n; i += 8) {
    int idx = i + g;
    bool ok = idx < n;
    int pk = csrp[lo + (ok ? idx : 0)];
    int uoff = pk & ~255;               // u*256: Hb row offset
    float s = ssrc[(pk >> 8) * NH + hA] + sd + sse[((pk & 255) << 3) + hA];
    s = s > 0.f ? s : LALPHA * s;
    float p = ok ? __expf(s) : 0.f;     // scores are O(2): exp safe without max-sub
#pragma unroll
    for (int e = 0; e < 8; ++e) {
      float pe = __shfl(p, e * 8 + g);           // p[edge=e][head=g]
      unsigned ue = (unsigned)__shfl(uoff, e * 8) + lane4;
      u2v x = *reinterpret_cast<const u2v*>(Hb + ue);
      a0 = fmaf(pe, u2f_lo(x.x), a0);
      a1 = fmaf(pe, u2f_hi(x.x), a1);
      a2 = fmaf(pe, u2f_lo(x.y), a2);
      a3 = fmaf(pe, u2f_hi(x.y), a3);
      dsum += pe;
    }
  }
  unsigned oi32 = (unsigned)v * OD + lane4;
  u2v rv = __builtin_nontemporal_load(reinterpret_cast<const u2v*>(Rb + oi32));
  float inv = (dsum > 0.f) ? 1.f / dsum : 0.f;   // no edges -> acc=0 -> o=r
  float o0 = fmaf(a0, inv, u2f_lo(rv.x));
  float o1 = fmaf(a1, inv, u2f_hi(rv.x));
  float o2 = fmaf(a2, inv, u2f_lo(rv.y));
  float o3 = fmaf(a3, inv, u2f_hi(rv.y));
  f4v wv;
  wv.x = o0 > 0.f ? o0 : expm1f(o0);
  wv.y = o1 > 0.f ? o1 : expm1f(o1);
  wv.z = o2 > 0.f ? o2 : expm1f(o2);
  wv.w = o3 > 0.f ? o3 : expm1f(o3);
  __builtin_nontemporal_store(wv, reinterpret_cast<f4v*>(out + (size_t)v * OD + lane4));
}

extern "C" void kernel_launch(void* const* d_in, const int* in_sizes, int n_in,
                              void* d_out, int out_size, void* d_ws, size_t ws_size,
                              hipStream_t stream) {
  const float* feat = (const float*)d_in[0];
  const int* src = (const int*)d_in[1];
  const int* dst = (const int*)d_in[2];
  const int* ety = (const int*)d_in[3];
  const float* Wfc = (const float*)d_in[4];
  const float* bfc = (const float*)d_in[5];
  const float* ee = (const float*)d_in[6];
  const float* attn = (const float*)d_in[7];
  const float* Wres = (const float*)d_in[8];
  const float* bres = (const float*)d_in[9];
  float* out = (float*)d_out;

  char* w = (char*)d_ws;
  unsigned short* Wtb   = (unsigned short*)w; w += (size_t)CD * IND * 2;
  unsigned short* Hb    = (unsigned short*)w; w += (size_t)NN * OD * 2;
  unsigned short* Rb    = (unsigned short*)w; w += (size_t)NN * OD * 2;
  float* ssrc = (float*)w; w += (size_t)NN * NH * 4;
  float* sdst = (float*)w; w += (size_t)NN * NH * 4;
  float* se   = (float*)w; w += 64 * 4;
  int* cnt    = (int*)w; w += (size_t)NN * 4;
  int* rk     = (int*)w; w += (size_t)NEDGE * 4;
  int* off    = (int*)w; w += (size_t)(SCAN_BLOCKS * 256) * 4;
  int* bsum   = (int*)w; w += 256 * 4;
  int* boff   = (int*)w; w += 256 * 4;
  int* done   = (int*)w; w += 256 * 4;
  int* csrp   = (int*)w; w += (size_t)NEDGE * 4;

  k_prep<<<(CD * IND) / 256, 256, 0, stream>>>(Wfc, Wres, Wtb, cnt, done);
  k_gemm<<<NBG + NBH, 512, 0, stream>>>(feat, Wtb, bfc, bres, attn,
                                        dst, cnt, rk, Hb, Rb, ssrc, sdst);
  k_scansc<<<SCAN_BLOCKS + 782, 256, 0, stream>>>(cnt, off, bsum, done, ee, attn,
                                                  se, boff, src, dst, ety, rk, csrp);
  k_fuse<<<NN / 4, 256, 0, stream>>>(Hb, Rb, csrp, ssrc, sdst, se, off, boff, out);
}

// Round 22
// 169.506 us; speedup vs baseline: 1.6942x; 1.6942x over previous
//
#include <hip/hip_runtime.h>
#include <hip/hip_bf16.h>
#include <cstdint>

#define NN 50000
#define NEDGE 800000
#define IND 256
#define NH 8
#define DHH 32
#define NET 8
#define LALPHA 0.2f
#define OD 256
#define CD 512
#define SCAN_BLOCKS 196   // 196*256 = 50176 >= NN+1
#define NBG 782           // gemm blocks: (NN+63)/64
#define NBH 782           // hist blocks: (NEDGE/4+255)/256

typedef __attribute__((ext_vector_type(8))) short short8;
typedef __attribute__((ext_vector_type(4))) float f32x4;
typedef __attribute__((ext_vector_type(4))) float f4v;
typedef __attribute__((ext_vector_type(2))) unsigned u2v;
typedef __attribute__((ext_vector_type(4))) int i4v;

__device__ __forceinline__ unsigned short f2bf(float x) {
  union { float f; unsigned u; } v; v.f = x;
  unsigned r = v.u + 0x7FFFu + ((v.u >> 16) & 1u);
  return (unsigned short)(r >> 16);
}
__device__ __forceinline__ float bf2f(unsigned short u) {
  union { unsigned u; float f; } v; v.u = ((unsigned)u) << 16;
  return v.f;
}
__device__ __forceinline__ float u2f_lo(unsigned w) {
  union { unsigned u; float f; } v; v.u = w << 16; return v.f;
}
__device__ __forceinline__ float u2f_hi(unsigned w) {
  union { unsigned u; float f; } v; v.u = w & 0xffff0000u; return v.f;
}

// ---- prep: W^T concat cast + zero cnt/done (memset folded in) ----
__global__ __launch_bounds__(256) void k_prep(const float* __restrict__ Wfc,
                                              const float* __restrict__ Wres,
                                              unsigned short* __restrict__ Wtb,
                                              int* __restrict__ cnt,
                                              int* __restrict__ done) {
  int id = blockIdx.x * 256 + threadIdx.x;
  int k = id >> 9;
  int c = id & 511;
  float v = (c < OD) ? Wfc[k * OD + c] : Wres[k * OD + (c - OD)];
  Wtb[(size_t)c * IND + k] = f2bf(v);
  if (id < NN / 4) {
    i4v z = {0, 0, 0, 0};
    *reinterpret_cast<i4v*>(cnt + id * 4) = z;
  }
  if (id == 0) *done = 0;
}

// ---- block-specialized: blocks <NBG do MFMA GEMM+scores (operand-swapped,
// coalesced 128B/row/stripe writes); blocks >=NBG do dst histogram + ranks.
__global__ __launch_bounds__(256, 4) void k_gemm(const float* __restrict__ Af,
                                                 const unsigned short* __restrict__ Bt,
                                                 const float* __restrict__ bfc,
                                                 const float* __restrict__ bres,
                                                 const float* __restrict__ attn,
                                                 const int* __restrict__ dst,
                                                 int* __restrict__ cnt,
                                                 int* __restrict__ rk,
                                                 unsigned short* __restrict__ Hb,
                                                 unsigned short* __restrict__ Rb,
                                                 float* __restrict__ ssrc,
                                                 float* __restrict__ sdst) {
  __shared__ unsigned short Bs[64][272];   // 34.8 KB; 272 keeps permuted reads bank-uniform
  int tid = threadIdx.x;

  if (blockIdx.x >= NBG) {
    // histogram block: 4 edges/thread, pure atomic work, no barriers
    int e0 = ((blockIdx.x - NBG) * 256 + tid) << 2;
    if (e0 < NEDGE) {
      i4v d4 = __builtin_nontemporal_load(reinterpret_cast<const i4v*>(dst + e0));
      i4v rv;
      rv.x = atomicAdd(&cnt[d4.x], 1);
      rv.y = atomicAdd(&cnt[d4.y], 1);
      rv.z = atomicAdd(&cnt[d4.z], 1);
      rv.w = atomicAdd(&cnt[d4.w], 1);
      __builtin_nontemporal_store(rv, reinterpret_cast<i4v*>(rk + e0));
    }
    return;
  }

  int wave = tid >> 6, lane = tid & 63;
  int row0 = blockIdx.x * 64;

  int sr = tid >> 2;          // staging: col 0..63
  int sc = (tid & 3) * 8;     // k offset

  int cl = lane & 15;         // this thread's row-within-wave (C^T layout)
  int q = lane >> 4;          // col-quarter 0..3
  int arow = row0 + wave * 16 + cl;
  int lrow = arow < NN ? arow : NN - 1;    // clamp loads; stores guarded
  int akof = q * 8;
  short8 areg[8];
#pragma unroll
  for (int ks = 0; ks < 8; ++ks) {
    const float* p = Af + (size_t)lrow * IND + ks * 32 + akof;
    float4 f0 = *reinterpret_cast<const float4*>(p);
    float4 f1 = *reinterpret_cast<const float4*>(p + 4);
    unsigned short t8[8] = {f2bf(f0.x), f2bf(f0.y), f2bf(f0.z), f2bf(f0.w),
                            f2bf(f1.x), f2bf(f1.y), f2bf(f1.z), f2bf(f1.w)};
    areg[ks] = *reinterpret_cast<short8*>(t8);
  }

  for (int bn = 0; bn < 8; ++bn) {
    if (bn) __syncthreads();
#pragma unroll
    for (int j = 0; j < 8; ++j) {
      int k = j * 32 + sc;
      short8 bv = *reinterpret_cast<const short8*>(Bt + (size_t)(bn * 64 + sr) * IND + k);
      *reinterpret_cast<short8*>(&Bs[sr][k]) = bv;
    }
    __syncthreads();

    f32x4 acc[4];
#pragma unroll
    for (int i = 0; i < 4; ++i) acc[i] = (f32x4){0.f, 0.f, 0.f, 0.f};
#pragma unroll
    for (int ks = 0; ks < 8; ++ks) {
#pragma unroll
      for (int nf = 0; nf < 4; ++nf) {
        // permuted col selection: thread ends up owning 16 contiguous cols
        int colsel = (cl & 12) * 4 + (nf << 2) + (cl & 3);
        short8 b = *reinterpret_cast<const short8*>(&Bs[colsel][ks * 32 + akof]);
        // swapped operands: acc[nf][r] = C[arow][bn*64 + q*16 + nf*4 + r]
        acc[nf] = __builtin_amdgcn_mfma_f32_16x16x32_bf16(b, areg[ks], acc[nf], 0, 0, 0);
      }
    }

    bool isH = (bn < 4);
    int g0 = bn * 64 + q * 16;
    float s0 = 0.f, d0 = 0.f;
    unsigned short o16[16];
    if (isH) {
      int h = bn * 2 + (q >> 1);
      int dd0 = (q & 1) * 16;
#pragma unroll
      for (int nf = 0; nf < 4; ++nf) {
        f4v b4 = *reinterpret_cast<const f4v*>(bfc + g0 + nf * 4);
        f4v as4 = *reinterpret_cast<const f4v*>(attn + h * 96 + dd0 + nf * 4);
        f4v ad4 = *reinterpret_cast<const f4v*>(attn + h * 96 + 32 + dd0 + nf * 4);
#pragma unroll
        for (int r = 0; r < 4; ++r) {
          float val = acc[nf][r] + b4[r];
          o16[nf * 4 + r] = f2bf(val);
          s0 = fmaf(val, as4[r], s0);
          d0 = fmaf(val, ad4[r], d0);
        }
      }
    } else {
#pragma unroll
      for (int nf = 0; nf < 4; ++nf) {
        f4v b4 = *reinterpret_cast<const f4v*>(bres + g0 - 256 + nf * 4);
#pragma unroll
        for (int r = 0; r < 4; ++r) {
          float val = acc[nf][r] + b4[r];
          o16[nf * 4 + r] = f2bf(val);
        }
      }
    }
    if (arow < NN) {
      unsigned short* dp = isH ? (Hb + (size_t)arow * 256 + g0)
                               : (Rb + (size_t)arow * 256 + (g0 - 256));
      *reinterpret_cast<short8*>(dp) = *reinterpret_cast<short8*>(o16);
      *reinterpret_cast<short8*>(dp + 8) = *reinterpret_cast<short8*>(o16 + 8);
    }
    if (isH) {
      s0 += __shfl_xor(s0, 16);   // combine the two col-halves of this head
      d0 += __shfl_xor(d0, 16);
      if (!(q & 1) && arow < NN) {
        int h = bn * 2 + (q >> 1);
        ssrc[arow * NH + h] = s0;
        sdst[arow * NH + h] = d0;
      }
    }
  }
}

// phase A+B fused: per-block exclusive scan; last-arriving block scans the
// block sums (acquire atomic loads — safe across non-coherent XCD L2s) + se.
__global__ __launch_bounds__(256) void k_scanA(const int* __restrict__ cnt,
                                               int* __restrict__ off,
                                               int* __restrict__ bsum,
                                               int* __restrict__ done,
                                               const float* __restrict__ ee,
                                               const float* __restrict__ attn,
                                               float* __restrict__ se,
                                               int* __restrict__ boff) {
  __shared__ int sh[256];
  __shared__ int lastFlag;
  int tid = threadIdx.x;
  int gi = blockIdx.x * 256 + tid;
  int c = (gi < NN) ? cnt[gi] : 0;
  sh[tid] = c;
  __syncthreads();
#pragma unroll
  for (int d = 1; d < 256; d <<= 1) {
    int v = (tid >= d) ? sh[tid - d] : 0;
    __syncthreads();
    sh[tid] += v;
    __syncthreads();
  }
  off[gi] = sh[tid] - c;
  if (tid == 255) {
    bsum[blockIdx.x] = sh[255];
    __threadfence();
    lastFlag = (atomicAdd(done, 1) == SCAN_BLOCKS - 1);
  }
  __syncthreads();
  if (!lastFlag) return;
  __threadfence();
  int cb = (tid < SCAN_BLOCKS)
               ? __hip_atomic_load(&bsum[tid], __ATOMIC_ACQUIRE, __HIP_MEMORY_SCOPE_AGENT)
               : 0;
  __syncthreads();
  sh[tid] = cb;
  __syncthreads();
#pragma unroll
  for (int d = 1; d < 256; d <<= 1) {
    int v = (tid >= d) ? sh[tid - d] : 0;
    __syncthreads();
    sh[tid] += v;
    __syncthreads();
  }
  boff[tid] = sh[tid] - cb;
  // se[et,h]: tid = h*32 + dd
  int h = tid >> 5, dd = tid & 31;
  float ae = attn[h * 96 + 64 + dd];
  for (int et = 0; et < NET; ++et) {
    float p = ee[et * OD + tid] * ae;
#pragma unroll
    for (int off2 = 16; off2; off2 >>= 1) p += __shfl_xor(p, off2, 32);
    if (dd == 0) se[et * NH + h] = p;
  }
}

// ---- minimal CSR scatter: 4B per edge, csrp[pos] = (src<<8)|ety ----
__global__ __launch_bounds__(256) void k_scatter(const int* __restrict__ src,
                                                 const int* __restrict__ dst,
                                                 const int* __restrict__ ety,
                                                 const int* __restrict__ rk,
                                                 const int* __restrict__ off,
                                                 const int* __restrict__ boff,
                                                 int* __restrict__ csrp) {
  int t = blockIdx.x * 256 + threadIdx.x;
  int e0 = t << 2;
  if (e0 >= NEDGE) return;
  i4v s4 = __builtin_nontemporal_load(reinterpret_cast<const i4v*>(src + e0));
  i4v d4 = __builtin_nontemporal_load(reinterpret_cast<const i4v*>(dst + e0));
  i4v t4 = __builtin_nontemporal_load(reinterpret_cast<const i4v*>(ety + e0));
  i4v r4 = __builtin_nontemporal_load(reinterpret_cast<const i4v*>(rk + e0));
#pragma unroll
  for (int j = 0; j < 4; ++j) {
    int s = (j == 0) ? s4.x : (j == 1) ? s4.y : (j == 2) ? s4.z : s4.w;
    int d = (j == 0) ? d4.x : (j == 1) ? d4.y : (j == 2) ? d4.z : d4.w;
    int et = (j == 0) ? t4.x : (j == 1) ? t4.y : (j == 2) ? t4.z : t4.w;
    int r = (j == 0) ? r4.x : (j == 1) ? r4.y : (j == 2) ? r4.z : r4.w;
    csrp[off[d] + boff[d >> 8] + r] = (s << 8) | et;
  }
}

// ---- fused edge-scoring + aggregation: 1 wave/node; per 8-edge chunk,
// subphase A computes p(edge=g, head=lane&7) [csrp linear, ssrc L2 gather,
// exp], then __shfl redistributes p / gather-offset to the agg lanes.
__global__ __launch_bounds__(256) void k_fuse(const unsigned short* __restrict__ Hb,
                                              const unsigned short* __restrict__ Rb,
                                              const int* __restrict__ csrp,
                                              const float* __restrict__ ssrc,
                                              const float* __restrict__ sdst,
                                              const float* __restrict__ se,
                                              const int* __restrict__ off,
                                              const int* __restrict__ boff,
                                              float* __restrict__ out) {
  __shared__ float sse[64];
  int tid = threadIdx.x;
  if (tid < 64) sse[tid] = se[tid];
  __syncthreads();
  int v = blockIdx.x * 4 + (tid >> 6);
  int lane = tid & 63;
  int g = lane >> 3;       // subphase A: edge slot; agg phase: head (same value)
  int hA = lane & 7;       // subphase A: head
  int lo = off[v] + boff[v >> 8];
  int hi = off[v + 1] + boff[(v + 1) >> 8];
  int n = hi - lo;
  float sd = sdst[v * NH + hA];
  unsigned lane4 = (unsigned)(lane << 2);
  float a0 = 0.f, a1 = 0.f, a2 = 0.f, a3 = 0.f, dsum = 0.f;
  for (int i = 0; i < n; i += 8) {
    int idx = i + g;
    bool ok = idx < n;
    int pk = csrp[lo + (ok ? idx : 0)];
    int uoff = pk & ~255;               // u*256: Hb row offset
    float s = ssrc[(pk >> 8) * NH + hA] + sd + sse[((pk & 255) << 3) + hA];
    s = s > 0.f ? s : LALPHA * s;
    float p = ok ? __expf(s) : 0.f;     // scores are O(2): exp safe without max-sub
#pragma unroll
    for (int e = 0; e < 8; ++e) {
      float pe = __shfl(p, e * 8 + g);           // p[edge=e][head=g]
      unsigned ue = (unsigned)__shfl(uoff, e * 8) + lane4;
      u2v x = *reinterpret_cast<const u2v*>(Hb + ue);
      a0 = fmaf(pe, u2f_lo(x.x), a0);
      a1 = fmaf(pe, u2f_hi(x.x), a1);
      a2 = fmaf(pe, u2f_lo(x.y), a2);
      a3 = fmaf(pe, u2f_hi(x.y), a3);
      dsum += pe;
    }
  }
  unsigned oi32 = (unsigned)v * OD + lane4;
  u2v rv = __builtin_nontemporal_load(reinterpret_cast<const u2v*>(Rb + oi32));
  float inv = (dsum > 0.f) ? 1.f / dsum : 0.f;   // no edges -> acc=0 -> o=r
  float o0 = fmaf(a0, inv, u2f_lo(rv.x));
  float o1 = fmaf(a1, inv, u2f_hi(rv.x));
  float o2 = fmaf(a2, inv, u2f_lo(rv.y));
  float o3 = fmaf(a3, inv, u2f_hi(rv.y));
  f4v wv;
  wv.x = o0 > 0.f ? o0 : expm1f(o0);
  wv.y = o1 > 0.f ? o1 : expm1f(o1);
  wv.z = o2 > 0.f ? o2 : expm1f(o2);
  wv.w = o3 > 0.f ? o3 : expm1f(o3);
  __builtin_nontemporal_store(wv, reinterpret_cast<f4v*>(out + (size_t)v * OD + lane4));
}

extern "C" void kernel_launch(void* const* d_in, const int* in_sizes, int n_in,
                              void* d_out, int out_size, void* d_ws, size_t ws_size,
                              hipStream_t stream) {
  const float* feat = (const float*)d_in[0];
  const int* src = (const int*)d_in[1];
  const int* dst = (const int*)d_in[2];
  const int* ety = (const int*)d_in[3];
  const float* Wfc = (const float*)d_in[4];
  const float* bfc = (const float*)d_in[5];
  const float* ee = (const float*)d_in[6];
  const float* attn = (const float*)d_in[7];
  const float* Wres = (const float*)d_in[8];
  const float* bres = (const float*)d_in[9];
  float* out = (float*)d_out;

  char* w = (char*)d_ws;
  unsigned short* Wtb   = (unsigned short*)w; w += (size_t)CD * IND * 2;
  unsigned short* Hb    = (unsigned short*)w; w += (size_t)NN * OD * 2;
  unsigned short* Rb    = (unsigned short*)w; w += (size_t)NN * OD * 2;
  float* ssrc = (float*)w; w += (size_t)NN * NH * 4;
  float* sdst = (float*)w; w += (size_t)NN * NH * 4;
  float* se   = (float*)w; w += 64 * 4;
  int* cnt    = (int*)w; w += (size_t)NN * 4;
  int* rk     = (int*)w; w += (size_t)NEDGE * 4;
  int* off    = (int*)w; w += (size_t)(SCAN_BLOCKS * 256) * 4;
  int* bsum   = (int*)w; w += 256 * 4;
  int* boff   = (int*)w; w += 256 * 4;
  int* done   = (int*)w; w += 256 * 4;
  int* csrp   = (int*)w; w += (size_t)NEDGE * 4;

  k_prep<<<(CD * IND) / 256, 256, 0, stream>>>(Wfc, Wres, Wtb, cnt, done);
  k_gemm<<<NBG + NBH, 256, 0, stream>>>(feat, Wtb, bfc, bres, attn,
                                        dst, cnt, rk, Hb, Rb, ssrc, sdst);
  k_scanA<<<SCAN_BLOCKS, 256, 0, stream>>>(cnt, off, bsum, done, ee, attn, se, boff);
  k_scatter<<<(NEDGE / 4 + 255) / 256, 256, 0, stream>>>(src, dst, ety, rk,
                                                         off, boff, csrp);
  k_fuse<<<NN / 4, 256, 0, stream>>>(Hb, Rb, csrp, ssrc, sdst, se, off, boff, out);
}